// Round 1
// baseline (383.426 us; speedup 1.0000x reference)
//
#include <hip/hip_runtime.h>
#include <cstdint>
#include <cstddef>

#define LQ   2048
#define BQ   4
#define EQ   1024
#define HQ   8
#define D1Q  2048
#define HDQ  256
#define NBQ  (LQ*BQ)   // 8192 rows in (n,b) layout

typedef __bf16 bf16_t;
typedef __bf16 bf16x8 __attribute__((ext_vector_type(8)));
typedef __bf16 bf16x4 __attribute__((ext_vector_type(4)));
typedef float  f32x4  __attribute__((ext_vector_type(4)));

#define GAS1(p) ((const __attribute__((address_space(1))) void*)(p))
#define LAS3(p) ((__attribute__((address_space(3))) void*)(p))

// ---------------------------------------------------------------- utilities

__global__ __launch_bounds__(256) void convert_kernel(
    const float* __restrict__ Wu, const float* __restrict__ Wv,
    const float* __restrict__ Wo, const float* __restrict__ zero,
    const float* __restrict__ pos,
    bf16_t* __restrict__ Wub, bf16_t* __restrict__ Wvb,
    bf16_t* __restrict__ Wob, bf16_t* __restrict__ coef)
{
    const size_t i = (size_t)blockIdx.x * 256 + threadIdx.x;   // grid covers 2097152
    if (i < (size_t)D1Q * EQ) {
        Wub[i] = (bf16_t)Wu[i];
        Wvb[i] = (bf16_t)Wv[i];
        Wob[i] = (bf16_t)Wo[i];
    }
    if (i < (size_t)HQ * LQ) {
        const int h = (int)(i / LQ), j = (int)(i % LQ);
        const float c = (j == 0) ? zero[h] : pos[(size_t)h * (LQ - 1) + j - 1];
        coef[i] = (bf16_t)c;
    }
}

__global__ __launch_bounds__(256) void rmsnorm_kernel(
    const float* __restrict__ x, bf16_t* __restrict__ xn)
{
    const int row = blockIdx.x;           // 0..8191  (n*B + b)
    const int tid = threadIdx.x;
    const float4 v = ((const float4*)(x + (size_t)row * EQ))[tid];
    float ss = v.x*v.x + v.y*v.y + v.z*v.z + v.w*v.w;
    #pragma unroll
    for (int m = 32; m >= 1; m >>= 1) ss += __shfl_xor(ss, m, 64);
    __shared__ float red[4];
    const int wid = tid >> 6, lane = tid & 63;
    if (lane == 0) red[wid] = ss;
    __syncthreads();
    const float tot = red[0] + red[1] + red[2] + red[3];
    const float inv = 1.f / (sqrtf(tot * (1.f / EQ)) + 1e-8f);
    bf16x4 o;
    o[0] = (bf16_t)(v.x * inv); o[1] = (bf16_t)(v.y * inv);
    o[2] = (bf16_t)(v.z * inv); o[3] = (bf16_t)(v.w * inv);
    *(bf16x4*)(xn + (size_t)row * EQ + tid * 4) = o;
}

// V (n*B+b, h*HD+hd) -> VT (bh, hd, s)   64x64 tiles through LDS
__global__ __launch_bounds__(256) void transpose_v(
    const bf16_t* __restrict__ V, bf16_t* __restrict__ VT)
{
    __shared__ bf16_t tile[64][65];
    const int bh = blockIdx.z;                 // b*H + h
    const int b = bh >> 3, h = bh & 7;
    const int s0 = blockIdx.x * 64, hd0 = blockIdx.y * 64;
    const int tid = threadIdx.x;
    #pragma unroll
    for (int p = 0; p < 16; ++p) {
        const int idx = p * 256 + tid;
        const int i = idx >> 6;   // s
        const int j = idx & 63;   // hd
        tile[i][j] = V[((size_t)(s0 + i) * BQ + b) * D1Q + h * HDQ + hd0 + j];
    }
    __syncthreads();
    #pragma unroll
    for (int p = 0; p < 16; ++p) {
        const int idx = p * 256 + tid;
        const int i = idx >> 6;   // hd
        const int j = idx & 63;   // s
        VT[((size_t)bh * HDQ + hd0 + i) * LQ + s0 + j] = tile[j][i];
    }
}

// ---------------------------------------------------------------- GEMMs
// bt-GEMM: C[m,n] = sum_k A[m,k]*B[n,k]  (both K-contiguous), 128x128 tile,
// BK=32, 4 waves each owning a 64x64 quadrant of 4x4 16x16x32 MFMA frags.

template<int MODE>   // 0: silu(acc+bias)->bf16    2: acc+bias+res -> f32
__global__ __launch_bounds__(256) void gemm_bt(
    const bf16_t* __restrict__ A, const bf16_t* __restrict__ Bm,
    int M, int N, int K,
    const float* __restrict__ bias, const float* __restrict__ res,
    bf16_t* __restrict__ Cb, float* __restrict__ Cf)
{
    constexpr int BM = 128, BN = 128, BK = 32;
    __shared__ alignas(16) bf16_t As[BM * BK];
    __shared__ alignas(16) bf16_t Bs[BN * BK];

    const int tid  = threadIdx.x;
    const int wid  = tid >> 6;
    const int lane = tid & 63;
    const int m0 = blockIdx.y * BM;
    const int n0 = blockIdx.x * BN;
    const int wr = (wid >> 1) * 64;
    const int wc = (wid & 1) * 64;

    f32x4 acc[4][4];
    #pragma unroll
    for (int i = 0; i < 4; ++i)
        #pragma unroll
        for (int j = 0; j < 4; ++j) acc[i][j] = (f32x4){0.f, 0.f, 0.f, 0.f};

    // staging: tile is 8192B = 2 rounds x (4 waves x 64 lanes x 16B)
    const int off0 = wid * 1024 + lane * 16;
    const int off1 = off0 + 4096;
    const int r0 = off0 >> 6, c0 = off0 & 63;   // LDS row = 64B
    const int r1 = off1 >> 6, c1 = off1 & 63;
    const char* Ab = (const char*)(A + (size_t)m0 * K);
    const char* Bb = (const char*)(Bm + (size_t)n0 * K);
    const size_t ldb = (size_t)K * 2;

    const int frow = lane & 15;
    const int fk   = (lane >> 4) * 8;

    for (int k0 = 0; k0 < K; k0 += BK) {
        __builtin_amdgcn_global_load_lds(GAS1(Ab + (size_t)r0 * ldb + (size_t)k0 * 2 + c0),
                                         LAS3((char*)As + wid * 1024), 16, 0, 0);
        __builtin_amdgcn_global_load_lds(GAS1(Ab + (size_t)r1 * ldb + (size_t)k0 * 2 + c1),
                                         LAS3((char*)As + 4096 + wid * 1024), 16, 0, 0);
        __builtin_amdgcn_global_load_lds(GAS1(Bb + (size_t)r0 * ldb + (size_t)k0 * 2 + c0),
                                         LAS3((char*)Bs + wid * 1024), 16, 0, 0);
        __builtin_amdgcn_global_load_lds(GAS1(Bb + (size_t)r1 * ldb + (size_t)k0 * 2 + c1),
                                         LAS3((char*)Bs + 4096 + wid * 1024), 16, 0, 0);
        __syncthreads();

        bf16x8 af[4], bfv[4];
        #pragma unroll
        for (int i = 0; i < 4; ++i) {
            af[i]  = *(const bf16x8*)(As + (wr + i * 16 + frow) * BK + fk);
            bfv[i] = *(const bf16x8*)(Bs + (wc + i * 16 + frow) * BK + fk);
        }
        #pragma unroll
        for (int mi = 0; mi < 4; ++mi)
            #pragma unroll
            for (int ni = 0; ni < 4; ++ni)
                acc[mi][ni] = __builtin_amdgcn_mfma_f32_16x16x32_bf16(
                    af[mi], bfv[ni], acc[mi][ni], 0, 0, 0);
        __syncthreads();
    }

    // epilogue: C/D layout col = lane&15, row = (lane>>4)*4 + reg
    const int fq = (lane >> 4) * 4;
    #pragma unroll
    for (int mi = 0; mi < 4; ++mi) {
        #pragma unroll
        for (int ni = 0; ni < 4; ++ni) {
            const int gn = n0 + wc + ni * 16 + frow;
            #pragma unroll
            for (int j = 0; j < 4; ++j) {
                const int gm = m0 + wr + mi * 16 + fq + j;
                float v = acc[mi][ni][j];
                if constexpr (MODE == 0) {
                    v += bias[gn];
                    v = v / (1.f + __expf(-v));          // silu
                    Cb[(size_t)gm * N + gn] = (bf16_t)v;
                } else {
                    v += bias[gn] + res[(size_t)gm * N + gn];
                    Cf[(size_t)gm * N + gn] = v;
                }
            }
        }
    }
}

// Toeplitz GEMM per (b,h): out[t,hd] = sum_s coef[t-s] * v[s,hd], s<=t.
// A-tile (T matrix) synthesized into LDS from coef; B = VT (hd-major, s-contig).
// Epilogue fuses the u-gating and writes O in (n*B+b, d1) layout as bf16.
__global__ __launch_bounds__(256) void gemm_toep(
    const bf16_t* __restrict__ VT, const bf16_t* __restrict__ coef,
    const bf16_t* __restrict__ U, bf16_t* __restrict__ O)
{
    constexpr int BM = 128, BN = 128, BK = 32;
    __shared__ alignas(16) bf16_t As[BM * BK];
    __shared__ alignas(16) bf16_t Bs[BN * BK];

    const int tid  = threadIdx.x;
    const int wid  = tid >> 6;
    const int lane = tid & 63;
    const int m0 = blockIdx.y * BM;    // t block
    const int n0 = blockIdx.x * BN;    // hd block
    const int bh = blockIdx.z;
    const int b = bh >> 3, h = bh & 7;
    const int wr = (wid >> 1) * 64;
    const int wc = (wid & 1) * 64;

    f32x4 acc[4][4];
    #pragma unroll
    for (int i = 0; i < 4; ++i)
        #pragma unroll
        for (int j = 0; j < 4; ++j) acc[i][j] = (f32x4){0.f, 0.f, 0.f, 0.f};

    const int off0 = wid * 1024 + lane * 16;
    const int off1 = off0 + 4096;
    const int r0 = off0 >> 6, c0 = off0 & 63;
    const int r1 = off1 >> 6, c1 = off1 & 63;
    const char* Bb = (const char*)(VT + ((size_t)bh * HDQ + n0) * LQ);
    const size_t ldb = (size_t)LQ * 2;

    const bf16_t* ch = coef + h * LQ;
    const int arow  = tid >> 1;           // 0..127: row of A tile this thread fills
    const int kb    = (tid & 1) * 16;     // half-row
    const int t_row = m0 + arow;

    const int frow = lane & 15;
    const int fk   = (lane >> 4) * 8;
    const int kmax = m0 + BM;             // causal: tiles with s > t are all zero

    for (int k0 = 0; k0 < kmax; k0 += BK) {
        // synthesize A tile: As[r][k] = (t>=s) ? coef[t-s] : 0
        bf16x8 p0, p1;
        #pragma unroll
        for (int j = 0; j < 8; ++j) {
            const int d = t_row - (k0 + kb + j);
            const int dc = d < 0 ? 0 : d;
            const bf16_t cv = ch[dc];
            p0[j] = d < 0 ? (bf16_t)0.f : cv;
        }
        #pragma unroll
        for (int j = 0; j < 8; ++j) {
            const int d = t_row - (k0 + kb + 8 + j);
            const int dc = d < 0 ? 0 : d;
            const bf16_t cv = ch[dc];
            p1[j] = d < 0 ? (bf16_t)0.f : cv;
        }
        *(bf16x8*)(As + arow * BK + kb)     = p0;
        *(bf16x8*)(As + arow * BK + kb + 8) = p1;

        __builtin_amdgcn_global_load_lds(GAS1(Bb + (size_t)r0 * ldb + (size_t)k0 * 2 + c0),
                                         LAS3((char*)Bs + wid * 1024), 16, 0, 0);
        __builtin_amdgcn_global_load_lds(GAS1(Bb + (size_t)r1 * ldb + (size_t)k0 * 2 + c1),
                                         LAS3((char*)Bs + 4096 + wid * 1024), 16, 0, 0);
        __syncthreads();

        bf16x8 af[4], bfv[4];
        #pragma unroll
        for (int i = 0; i < 4; ++i) {
            af[i]  = *(const bf16x8*)(As + (wr + i * 16 + frow) * BK + fk);
            bfv[i] = *(const bf16x8*)(Bs + (wc + i * 16 + frow) * BK + fk);
        }
        #pragma unroll
        for (int mi = 0; mi < 4; ++mi)
            #pragma unroll
            for (int ni = 0; ni < 4; ++ni)
                acc[mi][ni] = __builtin_amdgcn_mfma_f32_16x16x32_bf16(
                    af[mi], bfv[ni], acc[mi][ni], 0, 0, 0);
        __syncthreads();
    }

    // epilogue: gate with u and scatter to (t*B+b, h*HD+hd)
    const int fq = (lane >> 4) * 4;
    #pragma unroll
    for (int mi = 0; mi < 4; ++mi) {
        #pragma unroll
        for (int ni = 0; ni < 4; ++ni) {
            const int hd = n0 + wc + ni * 16 + frow;
            #pragma unroll
            for (int j = 0; j < 4; ++j) {
                const int t = m0 + wr + mi * 16 + fq + j;
                const size_t idx = ((size_t)t * BQ + b) * D1Q + h * HDQ + hd;
                const float uval = (float)U[idx];
                O[idx] = (bf16_t)(uval * acc[mi][ni][j]);
            }
        }
    }
}

// ---------------------------------------------------------------- launch

extern "C" void kernel_launch(void* const* d_in, const int* in_sizes, int n_in,
                              void* d_out, int out_size, void* d_ws, size_t ws_size,
                              hipStream_t stream)
{
    const float* x    = (const float*)d_in[0];
    const float* Wu   = (const float*)d_in[1];
    const float* bu   = (const float*)d_in[2];
    const float* Wv   = (const float*)d_in[3];
    const float* bv   = (const float*)d_in[4];
    const float* Wo   = (const float*)d_in[5];
    const float* bo   = (const float*)d_in[6];
    const float* zero = (const float*)d_in[7];
    const float* pos  = (const float*)d_in[8];
    float* out = (float*)d_out;

    char* ws = (char*)d_ws;
    size_t off = 0;
    auto alloc = [&](size_t bytes) {
        char* p = ws + off;
        off += (bytes + 255) & ~(size_t)255;
        return p;
    };
    bf16_t* xn   = (bf16_t*)alloc((size_t)NBQ * EQ * 2);    // 16 MB
    bf16_t* Wub  = (bf16_t*)alloc((size_t)D1Q * EQ * 2);    //  4 MB
    bf16_t* Wvb  = (bf16_t*)alloc((size_t)D1Q * EQ * 2);    //  4 MB
    bf16_t* Wob  = (bf16_t*)alloc((size_t)EQ * D1Q * 2);    //  4 MB
    bf16_t* coef = (bf16_t*)alloc((size_t)HQ * LQ * 2);     // 32 KB
    bf16_t* Ub   = (bf16_t*)alloc((size_t)NBQ * D1Q * 2);   // 32 MB
    bf16_t* Vb   = (bf16_t*)alloc((size_t)NBQ * D1Q * 2);   // 32 MB
    bf16_t* VTb  = (bf16_t*)alloc((size_t)NBQ * D1Q * 2);   // 32 MB
    bf16_t* Ob   = (bf16_t*)alloc((size_t)NBQ * D1Q * 2);   // 32 MB

    convert_kernel<<<8192, 256, 0, stream>>>(Wu, Wv, Wo, zero, pos, Wub, Wvb, Wob, coef);
    rmsnorm_kernel<<<NBQ, 256, 0, stream>>>(x, xn);

    dim3 g1(D1Q / 128, NBQ / 128);   // (16, 64)
    gemm_bt<0><<<g1, 256, 0, stream>>>(xn, Wub, NBQ, D1Q, EQ, bu, nullptr, Ub, nullptr);
    gemm_bt<0><<<g1, 256, 0, stream>>>(xn, Wvb, NBQ, D1Q, EQ, bv, nullptr, Vb, nullptr);

    transpose_v<<<dim3(LQ / 64, HDQ / 64, BQ * HQ), 256, 0, stream>>>(Vb, VTb);

    gemm_toep<<<dim3(HDQ / 128, LQ / 128, BQ * HQ), 256, 0, stream>>>(VTb, coef, Ub, Ob);

    dim3 g2(EQ / 128, NBQ / 128);    // (8, 64)
    gemm_bt<2><<<g2, 256, 0, stream>>>(Ob, Wob, NBQ, EQ, D1Q, bo, x, nullptr, out);
}

// Round 2
// 272.093 us; speedup vs baseline: 1.4092x; 1.4092x over previous
//
#include <hip/hip_runtime.h>
#include <cstdint>
#include <cstddef>

#define LQ   2048
#define BQ   4
#define EQ   1024
#define HQ   8
#define D1Q  2048
#define HDQ  256
#define NBQ  (LQ*BQ)   // 8192 rows in (n,b) layout

typedef __bf16 bf16_t;
typedef __bf16 bf16x8 __attribute__((ext_vector_type(8)));
typedef __bf16 bf16x4 __attribute__((ext_vector_type(4)));
typedef float  f32x4  __attribute__((ext_vector_type(4)));

#define GAS1(p) ((const __attribute__((address_space(1))) void*)(p))
#define LAS3(p) ((__attribute__((address_space(3))) void*)(p))

// ---------------------------------------------------------------- utilities

__global__ __launch_bounds__(256) void convert_kernel(
    const float* __restrict__ Wu, const float* __restrict__ Wv,
    const float* __restrict__ Wo,
    bf16_t* __restrict__ Wub, bf16_t* __restrict__ Wvb,
    bf16_t* __restrict__ Wob)
{
    const size_t i = (size_t)blockIdx.x * 256 + threadIdx.x;
    if (i < (size_t)D1Q * EQ) {
        Wub[i] = (bf16_t)Wu[i];
        Wvb[i] = (bf16_t)Wv[i];
        Wob[i] = (bf16_t)Wo[i];
    }
}

// Precompute all Toeplitz A-tiles.  Tile q (q=0..63) of head h is the
// 128x32 tile with diagonal offset doff = (q-3)*32:
//   T[r][c] = coef[doff + r - c]  (0 if d<0), d guaranteed <= 2047.
__global__ __launch_bounds__(256) void build_toep_tiles(
    const float* __restrict__ zero, const float* __restrict__ pos,
    bf16_t* __restrict__ Atiles)
{
    const int q = blockIdx.x;        // 0..63
    const int h = blockIdx.y;        // 0..7
    const int doff = (q - 3) * 32;
    const int tid = threadIdx.x;
    bf16_t* dst = Atiles + ((size_t)h * 64 + q) * (128 * 32);
    const int e0 = tid * 16;                 // 16 contiguous elems per thread
    const int r = e0 >> 5;
    const int cbase = e0 & 31;               // 0 or 16
    bf16_t vals[16];
    #pragma unroll
    for (int j = 0; j < 16; ++j) {
        const int d = doff + r - (cbase + j);
        float v = 0.f;
        if (d == 0) v = zero[h];
        else if (d > 0) v = pos[(size_t)h * (LQ - 1) + d - 1];
        vals[j] = (bf16_t)v;
    }
    *(bf16x8*)(dst + e0)     = *(bf16x8*)(vals);
    *(bf16x8*)(dst + e0 + 8) = *(bf16x8*)(vals + 8);
}

__global__ __launch_bounds__(256) void rmsnorm_kernel(
    const float* __restrict__ x, bf16_t* __restrict__ xn)
{
    const int row = blockIdx.x;           // 0..8191  (n*B + b)
    const int tid = threadIdx.x;
    const float4 v = ((const float4*)(x + (size_t)row * EQ))[tid];
    float ss = v.x*v.x + v.y*v.y + v.z*v.z + v.w*v.w;
    #pragma unroll
    for (int m = 32; m >= 1; m >>= 1) ss += __shfl_xor(ss, m, 64);
    __shared__ float red[4];
    const int wid = tid >> 6, lane = tid & 63;
    if (lane == 0) red[wid] = ss;
    __syncthreads();
    const float tot = red[0] + red[1] + red[2] + red[3];
    const float inv = 1.f / (sqrtf(tot * (1.f / EQ)) + 1e-8f);
    bf16x4 o;
    o[0] = (bf16_t)(v.x * inv); o[1] = (bf16_t)(v.y * inv);
    o[2] = (bf16_t)(v.z * inv); o[3] = (bf16_t)(v.w * inv);
    *(bf16x4*)(xn + (size_t)row * EQ + tid * 4) = o;
}

// V (n*B+b, h*HD+hd) -> VT (bh, hd, s)   64x64 tiles through LDS
__global__ __launch_bounds__(256) void transpose_v(
    const bf16_t* __restrict__ V, bf16_t* __restrict__ VT)
{
    __shared__ bf16_t tile[64][65];
    const int bh = blockIdx.z;                 // b*H + h
    const int b = bh >> 3, h = bh & 7;
    const int s0 = blockIdx.x * 64, hd0 = blockIdx.y * 64;
    const int tid = threadIdx.x;
    #pragma unroll
    for (int p = 0; p < 16; ++p) {
        const int idx = p * 256 + tid;
        const int i = idx >> 6;   // s
        const int j = idx & 63;   // hd
        tile[i][j] = V[((size_t)(s0 + i) * BQ + b) * D1Q + h * HDQ + hd0 + j];
    }
    __syncthreads();
    #pragma unroll
    for (int p = 0; p < 16; ++p) {
        const int idx = p * 256 + tid;
        const int i = idx >> 6;   // hd
        const int j = idx & 63;   // s
        VT[((size_t)bh * HDQ + hd0 + i) * LQ + s0 + j] = tile[j][i];
    }
}

// ---------------------------------------------------------------- GEMMs
// bt-GEMM: C[m,n] = sum_k A[m,k]*B[n,k]  (both K-contiguous), 128x128 tile,
// BK=32, 4 waves each owning a 64x64 quadrant of 4x4 16x16x32 MFMA frags.

template<int MODE>   // 0: silu(acc+bias)->bf16    2: acc+bias+res -> f32
__global__ __launch_bounds__(256) void gemm_bt(
    const bf16_t* __restrict__ A, const bf16_t* __restrict__ Bm,
    int M, int N, int K,
    const float* __restrict__ bias, const float* __restrict__ res,
    bf16_t* __restrict__ Cb, float* __restrict__ Cf)
{
    constexpr int BM = 128, BN = 128, BK = 32;
    __shared__ alignas(16) bf16_t As[BM * BK];
    __shared__ alignas(16) bf16_t Bs[BN * BK];

    const int tid  = threadIdx.x;
    const int wid  = tid >> 6;
    const int lane = tid & 63;
    const int m0 = blockIdx.y * BM;
    const int n0 = blockIdx.x * BN;
    const int wr = (wid >> 1) * 64;
    const int wc = (wid & 1) * 64;

    f32x4 acc[4][4];
    #pragma unroll
    for (int i = 0; i < 4; ++i)
        #pragma unroll
        for (int j = 0; j < 4; ++j) acc[i][j] = (f32x4){0.f, 0.f, 0.f, 0.f};

    // staging: tile is 8192B = 2 rounds x (4 waves x 64 lanes x 16B)
    const int off0 = wid * 1024 + lane * 16;
    const int off1 = off0 + 4096;
    const int r0 = off0 >> 6, c0 = off0 & 63;   // LDS row = 64B
    const int r1 = off1 >> 6, c1 = off1 & 63;
    const char* Ab = (const char*)(A + (size_t)m0 * K);
    const char* Bb = (const char*)(Bm + (size_t)n0 * K);
    const size_t ldb = (size_t)K * 2;

    const int frow = lane & 15;
    const int fk   = (lane >> 4) * 8;

    for (int k0 = 0; k0 < K; k0 += BK) {
        __builtin_amdgcn_global_load_lds(GAS1(Ab + (size_t)r0 * ldb + (size_t)k0 * 2 + c0),
                                         LAS3((char*)As + wid * 1024), 16, 0, 0);
        __builtin_amdgcn_global_load_lds(GAS1(Ab + (size_t)r1 * ldb + (size_t)k0 * 2 + c1),
                                         LAS3((char*)As + 4096 + wid * 1024), 16, 0, 0);
        __builtin_amdgcn_global_load_lds(GAS1(Bb + (size_t)r0 * ldb + (size_t)k0 * 2 + c0),
                                         LAS3((char*)Bs + wid * 1024), 16, 0, 0);
        __builtin_amdgcn_global_load_lds(GAS1(Bb + (size_t)r1 * ldb + (size_t)k0 * 2 + c1),
                                         LAS3((char*)Bs + 4096 + wid * 1024), 16, 0, 0);
        __syncthreads();

        bf16x8 af[4], bfv[4];
        #pragma unroll
        for (int i = 0; i < 4; ++i) {
            af[i]  = *(const bf16x8*)(As + (wr + i * 16 + frow) * BK + fk);
            bfv[i] = *(const bf16x8*)(Bs + (wc + i * 16 + frow) * BK + fk);
        }
        #pragma unroll
        for (int mi = 0; mi < 4; ++mi)
            #pragma unroll
            for (int ni = 0; ni < 4; ++ni)
                acc[mi][ni] = __builtin_amdgcn_mfma_f32_16x16x32_bf16(
                    af[mi], bfv[ni], acc[mi][ni], 0, 0, 0);
        __syncthreads();
    }

    // epilogue: C/D layout col = lane&15, row = (lane>>4)*4 + reg
    const int fq = (lane >> 4) * 4;
    #pragma unroll
    for (int mi = 0; mi < 4; ++mi) {
        #pragma unroll
        for (int ni = 0; ni < 4; ++ni) {
            const int gn = n0 + wc + ni * 16 + frow;
            #pragma unroll
            for (int j = 0; j < 4; ++j) {
                const int gm = m0 + wr + mi * 16 + fq + j;
                float v = acc[mi][ni][j];
                if constexpr (MODE == 0) {
                    v += bias[gn];
                    v = v / (1.f + __expf(-v));          // silu
                    Cb[(size_t)gm * N + gn] = (bf16_t)v;
                } else {
                    v += bias[gn] + res[(size_t)gm * N + gn];
                    Cf[(size_t)gm * N + gn] = v;
                }
            }
        }
    }
}

// Toeplitz GEMM per (b,h): out[t,hd] = sum_s coef[t-s] * v[s,hd], s<=t.
// A staged from precomputed tiles (pure bt-GEMM); B = VT (hd-major, s-contig).
// 1-D grid, heavy blocks (large m0) dispatched first.
// Epilogue fuses the u-gating and writes O in (n*B+b, d1) layout as bf16.
__global__ __launch_bounds__(256) void gemm_toep(
    const bf16_t* __restrict__ VT, const bf16_t* __restrict__ Atiles,
    const bf16_t* __restrict__ U, bf16_t* __restrict__ O)
{
    constexpr int BM = 128, BN = 128, BK = 32;
    __shared__ alignas(16) bf16_t As[BM * BK];
    __shared__ alignas(16) bf16_t Bs[BN * BK];

    const int bid   = blockIdx.x;          // 0..1023
    const int m_blk = 15 - (bid >> 6);     // heavy-first
    const int sub   = bid & 63;
    const int bh    = sub >> 1;
    const int n0    = (sub & 1) * BN;
    const int b = bh >> 3, h = bh & 7;
    const int m0 = m_blk * BM;

    const int tid  = threadIdx.x;
    const int wid  = tid >> 6;
    const int lane = tid & 63;
    const int wr = (wid >> 1) * 64;
    const int wc = (wid & 1) * 64;

    f32x4 acc[4][4];
    #pragma unroll
    for (int i = 0; i < 4; ++i)
        #pragma unroll
        for (int j = 0; j < 4; ++j) acc[i][j] = (f32x4){0.f, 0.f, 0.f, 0.f};

    const int off0 = wid * 1024 + lane * 16;
    const int off1 = off0 + 4096;
    const int r0 = off0 >> 6, c0 = off0 & 63;
    const int r1 = off1 >> 6, c1 = off1 & 63;
    const char* Bb = (const char*)(VT + ((size_t)bh * HDQ + n0) * LQ);
    const size_t ldb = (size_t)LQ * 2;
    const char* Ah = (const char*)(Atiles + (size_t)h * 64 * 4096);

    const int frow = lane & 15;
    const int fk   = (lane >> 4) * 8;
    const int nk   = 4 * m_blk + 4;        // causal: only k0 <= m0+96

    for (int kq = 0; kq < nk; ++kq) {
        const int k0 = kq * 32;
        const char* At = Ah + (size_t)((m_blk << 2) + 3 - kq) * 8192;
        __builtin_amdgcn_global_load_lds(GAS1(At + off0),
                                         LAS3((char*)As + wid * 1024), 16, 0, 0);
        __builtin_amdgcn_global_load_lds(GAS1(At + off1),
                                         LAS3((char*)As + 4096 + wid * 1024), 16, 0, 0);
        __builtin_amdgcn_global_load_lds(GAS1(Bb + (size_t)r0 * ldb + (size_t)k0 * 2 + c0),
                                         LAS3((char*)Bs + wid * 1024), 16, 0, 0);
        __builtin_amdgcn_global_load_lds(GAS1(Bb + (size_t)r1 * ldb + (size_t)k0 * 2 + c1),
                                         LAS3((char*)Bs + 4096 + wid * 1024), 16, 0, 0);
        __syncthreads();

        bf16x8 af[4], bfv[4];
        #pragma unroll
        for (int i = 0; i < 4; ++i) {
            af[i]  = *(const bf16x8*)(As + (wr + i * 16 + frow) * BK + fk);
            bfv[i] = *(const bf16x8*)(Bs + (wc + i * 16 + frow) * BK + fk);
        }
        #pragma unroll
        for (int mi = 0; mi < 4; ++mi)
            #pragma unroll
            for (int ni = 0; ni < 4; ++ni)
                acc[mi][ni] = __builtin_amdgcn_mfma_f32_16x16x32_bf16(
                    af[mi], bfv[ni], acc[mi][ni], 0, 0, 0);
        __syncthreads();
    }

    // epilogue: gate with u and scatter to (t*B+b, h*HD+hd)
    const int fq = (lane >> 4) * 4;
    #pragma unroll
    for (int mi = 0; mi < 4; ++mi) {
        #pragma unroll
        for (int ni = 0; ni < 4; ++ni) {
            const int hd = n0 + wc + ni * 16 + frow;
            #pragma unroll
            for (int j = 0; j < 4; ++j) {
                const int t = m0 + wr + mi * 16 + fq + j;
                const size_t idx = ((size_t)t * BQ + b) * D1Q + h * HDQ + hd;
                const float uval = (float)U[idx];
                O[idx] = (bf16_t)(uval * acc[mi][ni][j]);
            }
        }
    }
}

// ---------------------------------------------------------------- launch

extern "C" void kernel_launch(void* const* d_in, const int* in_sizes, int n_in,
                              void* d_out, int out_size, void* d_ws, size_t ws_size,
                              hipStream_t stream)
{
    const float* x    = (const float*)d_in[0];
    const float* Wu   = (const float*)d_in[1];
    const float* bu   = (const float*)d_in[2];
    const float* Wv   = (const float*)d_in[3];
    const float* bv   = (const float*)d_in[4];
    const float* Wo   = (const float*)d_in[5];
    const float* bo   = (const float*)d_in[6];
    const float* zero = (const float*)d_in[7];
    const float* pos  = (const float*)d_in[8];
    float* out = (float*)d_out;

    char* ws = (char*)d_ws;
    size_t off = 0;
    auto alloc = [&](size_t bytes) {
        char* p = ws + off;
        off += (bytes + 255) & ~(size_t)255;
        return p;
    };
    bf16_t* xn     = (bf16_t*)alloc((size_t)NBQ * EQ * 2);     // 16 MB
    bf16_t* Wub    = (bf16_t*)alloc((size_t)D1Q * EQ * 2);     //  4 MB
    bf16_t* Wvb    = (bf16_t*)alloc((size_t)D1Q * EQ * 2);     //  4 MB
    bf16_t* Wob    = (bf16_t*)alloc((size_t)EQ * D1Q * 2);     //  4 MB
    bf16_t* Atiles = (bf16_t*)alloc((size_t)HQ * 64 * 4096 * 2); // 4 MB
    bf16_t* Ub     = (bf16_t*)alloc((size_t)NBQ * D1Q * 2);    // 32 MB
    bf16_t* Vb     = (bf16_t*)alloc((size_t)NBQ * D1Q * 2);    // 32 MB
    bf16_t* VTb    = (bf16_t*)alloc((size_t)NBQ * D1Q * 2);    // 32 MB
    bf16_t* Ob     = (bf16_t*)alloc((size_t)NBQ * D1Q * 2);    // 32 MB

    convert_kernel<<<8192, 256, 0, stream>>>(Wu, Wv, Wo, Wub, Wvb, Wob);
    build_toep_tiles<<<dim3(64, 8), 256, 0, stream>>>(zero, pos, Atiles);
    rmsnorm_kernel<<<NBQ, 256, 0, stream>>>(x, xn);

    dim3 g1(D1Q / 128, NBQ / 128);   // (16, 64)
    gemm_bt<0><<<g1, 256, 0, stream>>>(xn, Wub, NBQ, D1Q, EQ, bu, nullptr, Ub, nullptr);
    gemm_bt<0><<<g1, 256, 0, stream>>>(xn, Wvb, NBQ, D1Q, EQ, bv, nullptr, Vb, nullptr);

    transpose_v<<<dim3(LQ / 64, HDQ / 64, BQ * HQ), 256, 0, stream>>>(Vb, VTb);

    gemm_toep<<<1024, 256, 0, stream>>>(VTb, Atiles, Ub, Ob);

    dim3 g2(EQ / 128, NBQ / 128);    // (8, 64)
    gemm_bt<2><<<g2, 256, 0, stream>>>(Ob, Wob, NBQ, EQ, D1Q, bo, x, nullptr, out);
}

// Round 3
// 236.502 us; speedup vs baseline: 1.6212x; 1.1505x over previous
//
#include <hip/hip_runtime.h>
#include <cstdint>
#include <cstddef>

#define LQ   2048
#define BQ   4
#define EQ   1024
#define HQ   8
#define D1Q  2048
#define HDQ  256
#define NBQ  (LQ*BQ)   // 8192 rows in (n,b) layout

typedef __bf16 bf16_t;
typedef __bf16 bf16x8 __attribute__((ext_vector_type(8)));
typedef __bf16 bf16x4 __attribute__((ext_vector_type(4)));
typedef float  f32x4  __attribute__((ext_vector_type(4)));

#define GAS1(p) ((const __attribute__((address_space(1))) void*)(p))
#define LAS3(p) ((__attribute__((address_space(3))) void*)(p))

// ---------------------------------------------------------------- utilities

__global__ __launch_bounds__(256) void convert_kernel(
    const float* __restrict__ Wu, const float* __restrict__ Wv,
    const float* __restrict__ Wo,
    bf16_t* __restrict__ Wub, bf16_t* __restrict__ Wvb,
    bf16_t* __restrict__ Wob)
{
    const size_t i = (size_t)blockIdx.x * 256 + threadIdx.x;
    if (i < (size_t)D1Q * EQ) {
        Wub[i] = (bf16_t)Wu[i];
        Wvb[i] = (bf16_t)Wv[i];
        Wob[i] = (bf16_t)Wo[i];
    }
}

// Precompute all Toeplitz A-tiles (128x32, diagonal offset (q-3)*32).
__global__ __launch_bounds__(256) void build_toep_tiles(
    const float* __restrict__ zero, const float* __restrict__ pos,
    bf16_t* __restrict__ Atiles)
{
    const int q = blockIdx.x;        // 0..63
    const int h = blockIdx.y;        // 0..7
    const int doff = (q - 3) * 32;
    const int tid = threadIdx.x;
    bf16_t* dst = Atiles + ((size_t)h * 64 + q) * (128 * 32);
    const int e0 = tid * 16;
    const int r = e0 >> 5;
    const int cbase = e0 & 31;
    bf16_t vals[16];
    #pragma unroll
    for (int j = 0; j < 16; ++j) {
        const int d = doff + r - (cbase + j);
        float v = 0.f;
        if (d == 0) v = zero[h];
        else if (d > 0) v = pos[(size_t)h * (LQ - 1) + d - 1];
        vals[j] = (bf16_t)v;
    }
    *(bf16x8*)(dst + e0)     = *(bf16x8*)(vals);
    *(bf16x8*)(dst + e0 + 8) = *(bf16x8*)(vals + 8);
}

__global__ __launch_bounds__(256) void rmsnorm_kernel(
    const float* __restrict__ x, bf16_t* __restrict__ xn)
{
    const int row = blockIdx.x;           // 0..8191
    const int tid = threadIdx.x;
    const float4 v = ((const float4*)(x + (size_t)row * EQ))[tid];
    float ss = v.x*v.x + v.y*v.y + v.z*v.z + v.w*v.w;
    #pragma unroll
    for (int m = 32; m >= 1; m >>= 1) ss += __shfl_xor(ss, m, 64);
    __shared__ float red[4];
    const int wid = tid >> 6, lane = tid & 63;
    if (lane == 0) red[wid] = ss;
    __syncthreads();
    const float tot = red[0] + red[1] + red[2] + red[3];
    const float inv = 1.f / (sqrtf(tot * (1.f / EQ)) + 1e-8f);
    bf16x4 o;
    o[0] = (bf16_t)(v.x * inv); o[1] = (bf16_t)(v.y * inv);
    o[2] = (bf16_t)(v.z * inv); o[3] = (bf16_t)(v.w * inv);
    *(bf16x4*)(xn + (size_t)row * EQ + tid * 4) = o;
}

// V (n*B+b, h*HD+hd) -> VT (bh, hd, s)
__global__ __launch_bounds__(256) void transpose_v(
    const bf16_t* __restrict__ V, bf16_t* __restrict__ VT)
{
    __shared__ bf16_t tile[64][65];
    const int bh = blockIdx.z;
    const int b = bh >> 3, h = bh & 7;
    const int s0 = blockIdx.x * 64, hd0 = blockIdx.y * 64;
    const int tid = threadIdx.x;
    #pragma unroll
    for (int p = 0; p < 16; ++p) {
        const int idx = p * 256 + tid;
        const int i = idx >> 6;
        const int j = idx & 63;
        tile[i][j] = V[((size_t)(s0 + i) * BQ + b) * D1Q + h * HDQ + hd0 + j];
    }
    __syncthreads();
    #pragma unroll
    for (int p = 0; p < 16; ++p) {
        const int idx = p * 256 + tid;
        const int i = idx >> 6;
        const int j = idx & 63;
        VT[((size_t)bh * HDQ + hd0 + i) * LQ + s0 + j] = tile[j][i];
    }
}

// ---------------------------------------------------------------- 8-phase GEMM
// C[m,n] = sum_k A[m,k]*B[n,k], BM=256, BN=NREP*64, BK=32.
// 512 threads = 8 waves (2 M x 4 N), wave tile 128 x (NREP*16).
// Triple-buffered LDS, prefetch distance 2 K-tiles, counted vmcnt boundaries.
// LDS layout per operand: [rows][32 k] bf16, 64B rows, 16B slots XOR-swizzled
// by g(r) = (r ^ (r>>2)) & 3  (applied to pre-swizzled global source AND reads).

template<int NREP, int MODE>   // MODE 0: silu(acc+bias)->bf16   2: acc+bias+res->f32
__global__ __launch_bounds__(512, 1) void gemm8p(
    const bf16_t* __restrict__ A, const bf16_t* __restrict__ Bm,
    int K, int N,
    const float* __restrict__ bias, const float* __restrict__ res,
    bf16_t* __restrict__ Cb, float* __restrict__ Cf)
{
    constexpr int LB      = NREP / 2;            // B loads per K-tile (2 or 1)
    constexpr int BSTRIDE = 16384 + NREP * 4096; // bytes per buffer
    __shared__ alignas(16) char smem[3 * BSTRIDE];

    const int tid  = threadIdx.x;
    const int wid  = tid >> 6;
    const int lane = tid & 63;
    const int frow = lane & 15;
    const int c    = lane >> 4;
    const int m0 = blockIdx.y * 256;
    const int n0 = blockIdx.x * (NREP * 64);
    const int wrm = (wid >> 2) * 128;
    const int wrn = (wid & 3) * (NREP * 16);

    // fragment-read byte offsets (swizzled)
    const int Ra = wrm + frow;
    const int ga = (Ra ^ (Ra >> 2)) & 3;
    const int offA = Ra * 64 + ((c ^ ga) << 4);
    const int Rb = wrn + frow;
    const int gb = (Rb ^ (Rb >> 2)) & 3;
    const int offB = 16384 + Rb * 64 + ((c ^ gb) << 4);

    // staging: thread covers LDS bytes [tid*16, +16) (+8192 for 2nd load)
    const int sr   = tid >> 2;           // row 0..127 (+128 for 2nd load)
    const int slot = tid & 3;
    const int gs   = (sr ^ (sr >> 2)) & 3;
    const size_t lda = (size_t)K * 2;
    const char* srcA  = (const char*)A  + (size_t)(m0 + sr) * lda + ((slot ^ gs) << 4);
    const char* srcA2 = srcA + 128 * lda;
    const char* srcB  = (const char*)Bm + (size_t)(n0 + sr) * lda + ((slot ^ gs) << 4);
    const char* srcB2 = srcB + 128 * lda;

    auto STAGE_A = [&](int buf, int kt) {
        char* d = smem + buf * BSTRIDE + wid * 1024;
        __builtin_amdgcn_global_load_lds(GAS1(srcA  + (size_t)kt * 64), LAS3(d), 16, 0, 0);
        __builtin_amdgcn_global_load_lds(GAS1(srcA2 + (size_t)kt * 64), LAS3(d + 8192), 16, 0, 0);
    };
    auto STAGE_B = [&](int buf, int kt) {
        char* d = smem + buf * BSTRIDE + 16384 + wid * 1024;
        __builtin_amdgcn_global_load_lds(GAS1(srcB  + (size_t)kt * 64), LAS3(d), 16, 0, 0);
        if constexpr (LB == 2)
            __builtin_amdgcn_global_load_lds(GAS1(srcB2 + (size_t)kt * 64), LAS3(d + 8192), 16, 0, 0);
    };

    f32x4 acc[8][NREP];
    #pragma unroll
    for (int i = 0; i < 8; ++i)
        #pragma unroll
        for (int j = 0; j < NREP; ++j) acc[i][j] = (f32x4){0.f, 0.f, 0.f, 0.f};

    const int NT = K >> 5;

    // prologue: tiles 0,1
    STAGE_A(0, 0); STAGE_B(0, 0);
    STAGE_A(1, 1); STAGE_B(1, 1);
    if constexpr (LB == 2) asm volatile("s_waitcnt vmcnt(4)" ::: "memory");
    else                   asm volatile("s_waitcnt vmcnt(3)" ::: "memory");
    __builtin_amdgcn_s_barrier();

    int buf = 0;
    for (int kq = 0; kq < NT; ++kq) {
        const char* base = smem + buf * BSTRIDE;
        int pbuf = buf + 2; if (pbuf >= 3) pbuf -= 3;
        const bool pf = (kq < NT - 2);

        // ---- phase 1: read A[0-3], B[0..NREP-1]; prefetch A(kq+2); MFMA m0-3
        bf16x8 av[4], bv[NREP];
        #pragma unroll
        for (int i = 0; i < 4; ++i)
            av[i] = *(const bf16x8*)(base + offA + i * 1024);
        #pragma unroll
        for (int i = 0; i < NREP; ++i)
            bv[i] = *(const bf16x8*)(base + offB + i * 1024);
        if (pf) STAGE_A(pbuf, kq + 2);
        __builtin_amdgcn_s_barrier();
        __builtin_amdgcn_s_setprio(1);
        #pragma unroll
        for (int mi = 0; mi < 4; ++mi)
            #pragma unroll
            for (int ni = 0; ni < NREP; ++ni)
                acc[mi][ni] = __builtin_amdgcn_mfma_f32_16x16x32_bf16(
                    av[mi], bv[ni], acc[mi][ni], 0, 0, 0);
        __builtin_amdgcn_s_setprio(0);
        __builtin_amdgcn_sched_barrier(0);
        __builtin_amdgcn_s_barrier();

        // ---- phase 2: read A[4-7]; prefetch B(kq+2); MFMA m4-7
        #pragma unroll
        for (int i = 0; i < 4; ++i)
            av[i] = *(const bf16x8*)(base + offA + (4 + i) * 1024);
        if (pf) STAGE_B(pbuf, kq + 2);
        __builtin_amdgcn_s_barrier();
        __builtin_amdgcn_s_setprio(1);
        #pragma unroll
        for (int mi = 0; mi < 4; ++mi)
            #pragma unroll
            for (int ni = 0; ni < NREP; ++ni)
                acc[4 + mi][ni] = __builtin_amdgcn_mfma_f32_16x16x32_bf16(
                    av[mi], bv[ni], acc[4 + mi][ni], 0, 0, 0);
        __builtin_amdgcn_s_setprio(0);
        __builtin_amdgcn_sched_barrier(0);

        if (kq < NT - 1) {
            if (kq <= NT - 3) {
                if constexpr (LB == 2) asm volatile("s_waitcnt vmcnt(4)" ::: "memory");
                else                   asm volatile("s_waitcnt vmcnt(3)" ::: "memory");
            } else {
                asm volatile("s_waitcnt vmcnt(0)" ::: "memory");
            }
            __builtin_amdgcn_s_barrier();
        }
        buf = (buf == 2) ? 0 : buf + 1;
    }

    // epilogue: C/D layout col(n)=frow, row(m)=(lane>>4)*4+j
    const int fq = (lane >> 4) * 4;
    #pragma unroll
    for (int mi = 0; mi < 8; ++mi) {
        #pragma unroll
        for (int ni = 0; ni < NREP; ++ni) {
            const int gn = n0 + wrn + ni * 16 + frow;
            #pragma unroll
            for (int j = 0; j < 4; ++j) {
                const int gm = m0 + wrm + mi * 16 + fq + j;
                float v = acc[mi][ni][j];
                if constexpr (MODE == 0) {
                    v += bias[gn];
                    v = v / (1.f + __expf(-v));
                    Cb[(size_t)gm * N + gn] = (bf16_t)v;
                } else {
                    v += bias[gn] + res[(size_t)gm * N + gn];
                    Cf[(size_t)gm * N + gn] = v;
                }
            }
        }
    }
}

// ---------------------------------------------------------------- Toeplitz GEMM
// (unchanged from R2: 128x128 tile, precomputed A-tiles, heavy-first 1-D grid)
__global__ __launch_bounds__(256) void gemm_toep(
    const bf16_t* __restrict__ VT, const bf16_t* __restrict__ Atiles,
    const bf16_t* __restrict__ U, bf16_t* __restrict__ O)
{
    constexpr int BM = 128, BN = 128, BK = 32;
    __shared__ alignas(16) bf16_t As[BM * BK];
    __shared__ alignas(16) bf16_t Bs[BN * BK];

    const int bid   = blockIdx.x;
    const int m_blk = 15 - (bid >> 6);
    const int sub   = bid & 63;
    const int bh    = sub >> 1;
    const int n0    = (sub & 1) * BN;
    const int b = bh >> 3, h = bh & 7;
    const int m0 = m_blk * BM;

    const int tid  = threadIdx.x;
    const int wid  = tid >> 6;
    const int lane = tid & 63;
    const int wr = (wid >> 1) * 64;
    const int wc = (wid & 1) * 64;

    f32x4 acc[4][4];
    #pragma unroll
    for (int i = 0; i < 4; ++i)
        #pragma unroll
        for (int j = 0; j < 4; ++j) acc[i][j] = (f32x4){0.f, 0.f, 0.f, 0.f};

    const int off0 = wid * 1024 + lane * 16;
    const int off1 = off0 + 4096;
    const int r0 = off0 >> 6, c0 = off0 & 63;
    const int r1 = off1 >> 6, c1 = off1 & 63;
    const char* Bb = (const char*)(VT + ((size_t)bh * HDQ + n0) * LQ);
    const size_t ldb = (size_t)LQ * 2;
    const char* Ah = (const char*)(Atiles + (size_t)h * 64 * 4096);

    const int frow = lane & 15;
    const int fk   = (lane >> 4) * 8;
    const int nk   = 4 * m_blk + 4;

    for (int kq = 0; kq < nk; ++kq) {
        const int k0 = kq * 32;
        const char* At = Ah + (size_t)((m_blk << 2) + 3 - kq) * 8192;
        __builtin_amdgcn_global_load_lds(GAS1(At + off0),
                                         LAS3((char*)As + wid * 1024), 16, 0, 0);
        __builtin_amdgcn_global_load_lds(GAS1(At + off1),
                                         LAS3((char*)As + 4096 + wid * 1024), 16, 0, 0);
        __builtin_amdgcn_global_load_lds(GAS1(Bb + (size_t)r0 * ldb + (size_t)k0 * 2 + c0),
                                         LAS3((char*)Bs + wid * 1024), 16, 0, 0);
        __builtin_amdgcn_global_load_lds(GAS1(Bb + (size_t)r1 * ldb + (size_t)k0 * 2 + c1),
                                         LAS3((char*)Bs + 4096 + wid * 1024), 16, 0, 0);
        __syncthreads();

        bf16x8 af[4], bfv[4];
        #pragma unroll
        for (int i = 0; i < 4; ++i) {
            af[i]  = *(const bf16x8*)(As + (wr + i * 16 + frow) * BK + fk);
            bfv[i] = *(const bf16x8*)(Bs + (wc + i * 16 + frow) * BK + fk);
        }
        #pragma unroll
        for (int mi = 0; mi < 4; ++mi)
            #pragma unroll
            for (int ni = 0; ni < 4; ++ni)
                acc[mi][ni] = __builtin_amdgcn_mfma_f32_16x16x32_bf16(
                    af[mi], bfv[ni], acc[mi][ni], 0, 0, 0);
        __syncthreads();
    }

    const int fq = (lane >> 4) * 4;
    #pragma unroll
    for (int mi = 0; mi < 4; ++mi) {
        #pragma unroll
        for (int ni = 0; ni < 4; ++ni) {
            const int hd = n0 + wc + ni * 16 + frow;
            #pragma unroll
            for (int j = 0; j < 4; ++j) {
                const int t = m0 + wr + mi * 16 + fq + j;
                const size_t idx = ((size_t)t * BQ + b) * D1Q + h * HDQ + hd;
                const float uval = (float)U[idx];
                O[idx] = (bf16_t)(uval * acc[mi][ni][j]);
            }
        }
    }
}

// ---------------------------------------------------------------- launch

extern "C" void kernel_launch(void* const* d_in, const int* in_sizes, int n_in,
                              void* d_out, int out_size, void* d_ws, size_t ws_size,
                              hipStream_t stream)
{
    const float* x    = (const float*)d_in[0];
    const float* Wu   = (const float*)d_in[1];
    const float* bu   = (const float*)d_in[2];
    const float* Wv   = (const float*)d_in[3];
    const float* bv   = (const float*)d_in[4];
    const float* Wo   = (const float*)d_in[5];
    const float* bo   = (const float*)d_in[6];
    const float* zero = (const float*)d_in[7];
    const float* pos  = (const float*)d_in[8];
    float* out = (float*)d_out;

    char* ws = (char*)d_ws;
    size_t off = 0;
    auto alloc = [&](size_t bytes) {
        char* p = ws + off;
        off += (bytes + 255) & ~(size_t)255;
        return p;
    };
    bf16_t* xn     = (bf16_t*)alloc((size_t)NBQ * EQ * 2);
    bf16_t* Wub    = (bf16_t*)alloc((size_t)D1Q * EQ * 2);
    bf16_t* Wvb    = (bf16_t*)alloc((size_t)D1Q * EQ * 2);
    bf16_t* Wob    = (bf16_t*)alloc((size_t)EQ * D1Q * 2);
    bf16_t* Atiles = (bf16_t*)alloc((size_t)HQ * 64 * 4096 * 2);
    bf16_t* Ub     = (bf16_t*)alloc((size_t)NBQ * D1Q * 2);
    bf16_t* Vb     = (bf16_t*)alloc((size_t)NBQ * D1Q * 2);
    bf16_t* VTb    = (bf16_t*)alloc((size_t)NBQ * D1Q * 2);
    bf16_t* Ob     = (bf16_t*)alloc((size_t)NBQ * D1Q * 2);

    convert_kernel<<<8192, 256, 0, stream>>>(Wu, Wv, Wo, Wub, Wvb, Wob);
    build_toep_tiles<<<dim3(64, 8), 256, 0, stream>>>(zero, pos, Atiles);
    rmsnorm_kernel<<<NBQ, 256, 0, stream>>>(x, xn);

    // U,V: M=8192, N=2048, K=1024 — 256x256 tiles, 256 blocks
    dim3 g1(D1Q / 256, NBQ / 256);   // (8, 32)
    gemm8p<4, 0><<<g1, 512, 0, stream>>>(xn, Wub, EQ, D1Q, bu, nullptr, Ub, nullptr);
    gemm8p<4, 0><<<g1, 512, 0, stream>>>(xn, Wvb, EQ, D1Q, bv, nullptr, Vb, nullptr);

    transpose_v<<<dim3(LQ / 64, HDQ / 64, BQ * HQ), 256, 0, stream>>>(Vb, VTb);

    gemm_toep<<<1024, 256, 0, stream>>>(VTb, Atiles, Ub, Ob);

    // final: M=8192, N=1024, K=2048 — 256x128 tiles, 256 blocks
    dim3 g2(EQ / 128, NBQ / 256);    // (8, 32)
    gemm8p<2, 2><<<g2, 512, 0, stream>>>(Ob, Wob, D1Q, EQ, bo, x, nullptr, out);
}